// Round 9
// baseline (232.512 us; speedup 1.0000x reference)
//
#include <hip/hip_runtime.h>
#include <hip/hip_bf16.h>

#define Bsz 4
#define Ssz 1024
#define Dsz 768
#define Hn 12
#define DKsz 64
#define NUMEMB 10

// d_ws layout (bytes)
#define IDX_OFF 64
#define K_OFF   4194368          // IDX_OFF + 4*1024*1024
#define V_OFF   10485824         // K_OFF + 4*1024*768*2
#define WBF_OFF 16777280         // V_OFF + 4*1024*768*2
#define XBF_OFF 20316224         // WBF_OFF + 3*768*768*2
#define WS_TIER_B 20316224ULL    // enough for Wbf
#define WS_TIER_A 39190592ULL    // enough for Wbf + Xbf
// attention K-split partials overlay the (dead-by-then) Wbf/Xbf region:
#define PML_OFF 16777280         // 8*12*1024*2 fp32 = 786,432 B
#define PO_OFF  17563712         // 8*12*1024*64 bf16 = 12,582,912 B (end 30.1 MB < TIER_A)

#define NXz 3145728              // elems per X tensor (4*1024*768)
#define NWz 589824               // elems per W tensor (768*768)

#define IPAD 80                  // idx tile row stride (bytes)

typedef __attribute__((ext_vector_type(8))) short short8;
typedef __attribute__((ext_vector_type(8))) float float8;
typedef __attribute__((ext_vector_type(4))) float f32x4;
typedef __attribute__((ext_vector_type(4))) unsigned int u32x4;

__device__ __forceinline__ float bfbits2f(short u) {
    union { unsigned int i; float f; } v;
    v.i = ((unsigned int)(unsigned short)u) << 16;
    return v.f;
}
__device__ __forceinline__ unsigned short f2bf_bits(float f) {
    __hip_bfloat16 h = __float2bfloat16(f);
    return *reinterpret_cast<unsigned short*>(&h);
}

// DPP lane permute within 16-lane rows (VALU pipe)
template<int CTRL>
__device__ __forceinline__ float dppf(float x) {
    int xi = __float_as_int(x);
    int r = __builtin_amdgcn_update_dpp(xi, xi, CTRL, 0xF, 0xF, true);
    return __int_as_float(r);
}
__device__ __forceinline__ float red_max16(float v) {
    v = fmaxf(v, dppf<0xB1>(v));
    v = fmaxf(v, dppf<0x4E>(v));
    v = fmaxf(v, dppf<0x124>(v));
    v = fmaxf(v, dppf<0x128>(v));
    return v;
}
__device__ __forceinline__ float red_sum16(float v) {
    v += dppf<0xB1>(v);
    v += dppf<0x4E>(v);
    v += dppf<0x124>(v);
    v += dppf<0x128>(v);
    return v;
}

// dtype-dispatched loads: idx is an ELEMENT index
template<bool BF16>
__device__ __forceinline__ float loadf(const void* base, size_t idx) {
    if constexpr (BF16) return __bfloat162float(((const __hip_bfloat16*)base)[idx]);
    else return ((const float*)base)[idx];
}
template<bool BF16>
__device__ __forceinline__ short8 load8bf(const void* base, size_t idx) {
    if constexpr (BF16) {
        return *(const short8*)((const short*)base + idx);
    } else {
        float8 f = *(const float8*)((const float*)base + idx);
        short8 r;
#pragma unroll
        for (int i = 0; i < 8; i++) r[i] = (short)f2bf_bits(f[i]);
        return r;
    }
}
template<bool BF16>
__device__ __forceinline__ float8 load8f(const void* base, size_t idx) {
    if constexpr (BF16) {
        short8 s = *(const short8*)((const short*)base + idx);
        float8 f;
#pragma unroll
        for (int i = 0; i < 8; i++) f[i] = bfbits2f(s[i]);
        return f;
    } else {
        return *(const float8*)((const float*)base + idx);
    }
}

// ---------------- dtype detector ------------------------------------------
__global__ __launch_bounds__(64) void detect_kernel(
    const unsigned int* __restrict__ q, const unsigned int* __restrict__ p,
    const unsigned int* __restrict__ w, const unsigned int* __restrict__ e,
    int* __restrict__ flags)
{
    const int which = blockIdx.x;
    const unsigned int* ptr = (which == 0) ? q : ((which == 1) ? p : ((which == 2) ? w : e));
    const int n = (which == 3) ? 320 : ((which == 1) ? 4096 : 1024);
    int cnt = 0;
    for (int i = threadIdx.x; i < n; i += 64) {
        const unsigned int ex = (ptr[i] >> 7) & 0xFF;
        cnt += (ex >= 110 && ex <= 145) ? 1 : 0;
    }
#pragma unroll
    for (int off = 1; off < 64; off <<= 1) cnt += __shfl_xor(cnt, off, 64);
    if (threadIdx.x == 0) flags[which] = (2 * cnt > n) ? 1 : 0;
}

// ---------------- one-time bf16 canonicalization of X / W ------------------
__global__ __launch_bounds__(256) void conv_kernel(
    const void* __restrict__ X0, const void* __restrict__ X1, const void* __restrict__ X2,
    const void* __restrict__ W0, const void* __restrict__ W1, const void* __restrict__ W2,
    const int* __restrict__ flags, short* __restrict__ Xbf, short* __restrict__ Wbf,
    int doX)
{
    const long t = (long)blockIdx.x * 256 + threadIdx.x;
    const bool xb = flags[0] != 0, wb = flags[2] != 0;
    if (doX) {
        const long i8 = t * 8;
        if (i8 < (long)3 * NXz) {
            const int z = (int)(i8 / NXz);
            const long off = i8 - (long)z * NXz;
            const void* X = (z == 0) ? X0 : ((z == 1) ? X1 : X2);
            short8 v = xb ? load8bf<true>(X, off) : load8bf<false>(X, off);
            *(short8*)(Xbf + i8) = v;
        } else {
            const long j = i8 - (long)3 * NXz;
            const int z = (int)(j / NWz);
            const long off = j - (long)z * NWz;
            const void* W = (z == 0) ? W0 : ((z == 1) ? W1 : W2);
            short8 v = wb ? load8bf<true>(W, off) : load8bf<false>(W, off);
            *(short8*)(Wbf + j) = v;
        }
    } else {
        const long j = t * 8;
        const int z = (int)(j / NWz);
        const long off = j - (long)z * NWz;
        const void* W = (z == 0) ? W0 : ((z == 1) ? W1 : W2);
        short8 v = wb ? load8bf<true>(W, off) : load8bf<false>(W, off);
        *(short8*)(Wbf + j) = v;
    }
}

// ---------------- idx precompute: idx[b][i][j], uint8 ----------------------
// Exact fp32 op chain matching numpy; matrix is bitwise symmetric.
// Positions staged via LDS (2 coalesced loads/thread instead of ~17 scalar).
template<bool PB>
__device__ __forceinline__ void idx_body(
    const void* pos, unsigned char* __restrict__ idxb, float* qp, float* kp)
{
    const int kt = blockIdx.x, qt = blockIdx.y, b = blockIdx.z;
    const int t = threadIdx.x;
    if (t < 128) {
        const int row = t >> 1, c = t & 1;
        qp[t] = loadf<PB>(pos, ((size_t)b * Ssz + qt * 64 + row) * 2 + c);
    } else {
        const int t2 = t - 128;
        const int row = t2 >> 1, c = t2 & 1;
        kp[t2] = loadf<PB>(pos, ((size_t)b * Ssz + kt * 64 + row) * 2 + c);
    }
    __syncthreads();

    const int r = t >> 2, cc = t & 3;
    const int q = qt * 64 + r;
    const float qx = qp[r * 2], qy = qp[r * 2 + 1];
    const float MAXD = 141421.35623730951f;  // fp32(100000*sqrt(2))
    const int k0 = kt * 64 + cc * 16;
    unsigned int w[4];
#pragma unroll
    for (int g = 0; g < 4; g++) {
        unsigned int acc = 0;
#pragma unroll
        for (int u = 0; u < 4; u++) {
            const int kl = cc * 16 + g * 4 + u;   // local key 0..63
            const float kx = kp[kl * 2], ky = kp[kl * 2 + 1];
            const float dx = __fsub_rn(qx, kx);
            const float dy = __fsub_rn(qy, ky);
            const float ss = __fadd_rn(__fmul_rn(dx, dx), __fmul_rn(dy, dy));
            const float dist = __fdiv_rn(sqrtf(ss), MAXD);
            const float d9 = __fmul_rn(dist, 9.0f);
            int idx = (int)rintf(d9);
            idx = idx < 0 ? 0 : (idx > NUMEMB - 1 ? NUMEMB - 1 : idx);
            acc |= ((unsigned int)idx) << (8 * u);
        }
        w[g] = acc;
    }
    u32x4 v; v[0] = w[0]; v[1] = w[1]; v[2] = w[2]; v[3] = w[3];
    *(u32x4*)(idxb + ((size_t)(b * Ssz + q)) * Ssz + k0) = v;
}

__global__ __launch_bounds__(256) void idx_kernel(
    const void* pos, const int* __restrict__ flags, unsigned char* __restrict__ idxb)
{
    __shared__ __align__(16) float qp[128];
    __shared__ __align__(16) float kp[128];
    if (flags[1] != 0) idx_body<true >(pos, idxb, qp, kp);
    else               idx_body<false>(pos, idxb, qp, kp);
}

// ---------------- Projection GEMM: Y = X @ W^T + b -------------------------
// 64x128 tile, BK=64, reg-prefetch pipelined.
template<bool XB, bool WB>
__device__ __forceinline__ void proj_body(
    const void* X, const void* W, const void* bias, bool biasbf, void* Y, bool ybf,
    int bx, int by, short* As, short* Bs)
{
    const int tid  = threadIdx.x;
    const int wave = tid >> 6;
    const int lane = tid & 63;
    const int l15  = lane & 15;
    const int quad = lane >> 4;
    const int wm = wave & 1;
    const int wn = wave >> 1;
    const int m0 = bx * 64;
    const int n0 = by * 128;

    f32x4 acc[2][4];
#pragma unroll
    for (int i = 0; i < 2; i++)
#pragma unroll
        for (int j = 0; j < 4; j++) acc[i][j] = (f32x4)0.0f;

    const int r0 = tid >> 3;     // staging row 0..31
    const int cc = tid & 7;      // staging col-chunk (8 elems)

    short8 pa0 = load8bf<XB>(X, (size_t)(m0 + r0)      * Dsz + cc * 8);
    short8 pa1 = load8bf<XB>(X, (size_t)(m0 + 32 + r0) * Dsz + cc * 8);
    short8 pb0 = load8bf<WB>(W, (size_t)(n0 + r0)      * Dsz + cc * 8);
    short8 pb1 = load8bf<WB>(W, (size_t)(n0 + 32 + r0) * Dsz + cc * 8);
    short8 pb2 = load8bf<WB>(W, (size_t)(n0 + 64 + r0) * Dsz + cc * 8);
    short8 pb3 = load8bf<WB>(W, (size_t)(n0 + 96 + r0) * Dsz + cc * 8);

    for (int kk = 0; kk < Dsz; kk += 64) {
        __syncthreads();
        *(short8*)&As[(r0)      * 72 + cc * 8] = pa0;
        *(short8*)&As[(32 + r0) * 72 + cc * 8] = pa1;
        *(short8*)&Bs[(r0)      * 72 + cc * 8] = pb0;
        *(short8*)&Bs[(32 + r0) * 72 + cc * 8] = pb1;
        *(short8*)&Bs[(64 + r0) * 72 + cc * 8] = pb2;
        *(short8*)&Bs[(96 + r0) * 72 + cc * 8] = pb3;
        __syncthreads();

        if (kk + 64 < Dsz) {
            const int k2 = kk + 64 + cc * 8;
            pa0 = load8bf<XB>(X, (size_t)(m0 + r0)      * Dsz + k2);
            pa1 = load8bf<XB>(X, (size_t)(m0 + 32 + r0) * Dsz + k2);
            pb0 = load8bf<WB>(W, (size_t)(n0 + r0)      * Dsz + k2);
            pb1 = load8bf<WB>(W, (size_t)(n0 + 32 + r0) * Dsz + k2);
            pb2 = load8bf<WB>(W, (size_t)(n0 + 64 + r0) * Dsz + k2);
            pb3 = load8bf<WB>(W, (size_t)(n0 + 96 + r0) * Dsz + k2);
        }

#pragma unroll
        for (int st = 0; st < 2; st++) {   // k-order preserved
            short8 af[2], bf[4];
#pragma unroll
            for (int i = 0; i < 2; i++)
                af[i] = *(const short8*)&As[(wm * 32 + i * 16 + l15) * 72 + st * 32 + quad * 8];
#pragma unroll
            for (int j = 0; j < 4; j++)
                bf[j] = *(const short8*)&Bs[(wn * 64 + j * 16 + l15) * 72 + st * 32 + quad * 8];
#pragma unroll
            for (int i = 0; i < 2; i++)
#pragma unroll
                for (int j = 0; j < 4; j++)
                    acc[i][j] = __builtin_amdgcn_mfma_f32_16x16x32_bf16(af[i], bf[j], acc[i][j], 0, 0, 0);
        }
    }

#pragma unroll
    for (int j = 0; j < 4; j++) {
        const int n = n0 + wn * 64 + j * 16 + l15;
        const float bv_ = biasbf ? loadf<true>(bias, n) : loadf<false>(bias, n);
#pragma unroll
        for (int i = 0; i < 2; i++) {
#pragma unroll
            for (int r = 0; r < 4; r++) {
                const int m = m0 + wm * 32 + i * 16 + quad * 4 + r;
                const float val = acc[i][j][r] + bv_;
                if (ybf) ((__hip_bfloat16*)Y)[(size_t)m * Dsz + n] = __float2bfloat16(val);
                else     ((float*)Y)[(size_t)m * Dsz + n] = val;
            }
        }
    }
}

__global__ __launch_bounds__(256) void proj_kernel(
    const void* X0, const void* X1, const void* X2,
    const void* Wq, const void* bq, const void* Wk, const void* bk,
    const void* Wv, const void* bv,
    void* Qw, void* Kw, void* Vw, const int* __restrict__ flags,
    int fx, int fw)
{
    __shared__ __align__(16) short As[64 * 72];
    __shared__ __align__(16) short Bs[128 * 72];
    const int z = blockIdx.z;
    const void* X = (z == 0) ? X0 : ((z == 1) ? X1 : X2);
    const void* W = (z == 0) ? Wq : ((z == 1) ? Wk : Wv);
    const void* B = (z == 0) ? bq : ((z == 1) ? bk : bv);
    void* Y = (z == 0) ? Qw : ((z == 1) ? Kw : Vw);
    const bool xb = fx || flags[0] != 0;
    const bool wb = fw || flags[2] != 0;
    const bool biasbf = flags[2] != 0;
    const bool ybf = (flags[0] != 0) || (z != 0);
    if (xb) { if (wb) proj_body<true , true >(X, W, B, biasbf, Y, ybf, blockIdx.x, blockIdx.y, As, Bs);
              else    proj_body<true , false>(X, W, B, biasbf, Y, ybf, blockIdx.x, blockIdx.y, As, Bs); }
    else    { if (wb) proj_body<false, true >(X, W, B, biasbf, Y, ybf, blockIdx.x, blockIdx.y, As, Bs);
              else    proj_body<false, false>(X, W, B, biasbf, Y, ybf, blockIdx.x, blockIdx.y, As, Bs); }
}

// ---------------- Flash attention with distance-aware key bias --------------
// SPLIT: flash-decoding over 2 K-halves; partials (m,l fp32 + unnorm O bf16)
// to workspace, merged by combine_kernel.
template<bool QB, bool EB, bool SPLIT>
__device__ __forceinline__ void attn_body(
    const void* Qw, const short* __restrict__ Ks, const short* __restrict__ Vs,
    const unsigned char* __restrict__ idxb, const void* __restrict__ emb, void* out,
    float* __restrict__ pml, unsigned short* __restrict__ pO,
    unsigned short* Klds, unsigned short* Vtlds, unsigned short* Plds,
    float* qe, unsigned char* Ilds)
{
    const int qt = blockIdx.x, h = blockIdx.y;
    const int b    = SPLIT ? (blockIdx.z >> 1) : blockIdx.z;
    const int half = SPLIT ? (blockIdx.z & 1) : 0;
    const int itBeg = SPLIT ? half * 8 : 0;
    const int itEnd = itBeg + (SPLIT ? 8 : 16);
    const int tid  = threadIdx.x;
    const int wave = tid >> 6;
    const int lane = tid & 63;
    const int l15  = lane & 15;
    const int quad = lane >> 4;

    // qe[row][e] = 0.125 * sum_d Q[b, qrow, h*64+d] * emb[e][d]   (scale folded)
    for (int p = tid; p < 64 * NUMEMB; p += 256) {
        const int row = p / NUMEMB, e = p - row * NUMEMB;
        const size_t qoff = ((size_t)b * Ssz + qt * 64 + row) * Dsz + h * DKsz;
        float s = 0.f;
#pragma unroll
        for (int c = 0; c < 8; c++) {
            short8 qv = load8bf<QB>(Qw, qoff + c * 8);
            float8 ef = load8f<EB>(emb, (size_t)e * DKsz + c * 8);
#pragma unroll
            for (int i = 0; i < 8; i++) s += bfbits2f(qv[i]) * ef[i];
        }
        qe[p] = s * 0.125f;
    }

    short8 qfrag[2];
    {
        const size_t qbase = ((size_t)b * Ssz + qt * 64 + wave * 16 + l15) * Dsz + h * DKsz;
        qfrag[0] = load8bf<QB>(Qw, qbase + quad * 8);
        qfrag[1] = load8bf<QB>(Qw, qbase + 32 + quad * 8);
    }

    float m_run[4], l_run[4];
    f32x4 oacc[4];
#pragma unroll
    for (int r = 0; r < 4; r++) { m_run[r] = -1e30f; l_run[r] = 0.f; }
#pragma unroll
    for (int j = 0; j < 4; j++) oacc[j] = (f32x4)0.0f;

    const int srow = tid >> 3, schk = tid & 7;
    const int vp   = tid >> 3;
    const int irow = tid >> 2, ichk = tid & 3;

    short8 pk0, pk1, pv0, pv1;
    u32x4 pidx;
    {
        const size_t kb = ((size_t)b * Ssz + itBeg * 64) * Dsz + h * DKsz;
        pk0 = *(const short8*)(Ks + kb + (size_t)srow * Dsz + schk * 8);
        pk1 = *(const short8*)(Ks + kb + (size_t)(32 + srow) * Dsz + schk * 8);
        pv0 = *(const short8*)(Vs + kb + (size_t)(2 * vp) * Dsz + schk * 8);
        pv1 = *(const short8*)(Vs + kb + (size_t)(2 * vp + 1) * Dsz + schk * 8);
        pidx = *(const u32x4*)(idxb + ((size_t)(b * Ssz + itBeg * 64 + irow)) * Ssz + qt * 64 + ichk * 16);
    }

    for (int it = itBeg; it < itEnd; it++) {
        __syncthreads();
        *(short8*)&Klds[(srow)      * 72 + schk * 8] = pk0;
        *(short8*)&Klds[(32 + srow) * 72 + schk * 8] = pk1;
        {
            const int ssw = (2 * vp) ^ (schk << 3);
#pragma unroll
            for (int i = 0; i < 8; i++) {
                const unsigned int dw = (unsigned int)(unsigned short)pv0[i]
                                      | ((unsigned int)(unsigned short)pv1[i] << 16);
                *(unsigned int*)&Vtlds[(schk * 8 + i) * 72 + ssw] = dw;
            }
        }
        *(u32x4*)&Ilds[irow * IPAD + ichk * 16] = pidx;
        __syncthreads();

        if (it + 1 < itEnd) {
            const size_t kb = ((size_t)b * Ssz + (it + 1) * 64) * Dsz + h * DKsz;
            pk0 = *(const short8*)(Ks + kb + (size_t)srow * Dsz + schk * 8);
            pk1 = *(const short8*)(Ks + kb + (size_t)(32 + srow) * Dsz + schk * 8);
            pv0 = *(const short8*)(Vs + kb + (size_t)(2 * vp) * Dsz + schk * 8);
            pv1 = *(const short8*)(Vs + kb + (size_t)(2 * vp + 1) * Dsz + schk * 8);
            pidx = *(const u32x4*)(idxb + ((size_t)(b * Ssz + (it + 1) * 64 + irow)) * Ssz + qt * 64 + ichk * 16);
        }

        // S = Q K^T via MFMA
        f32x4 sf[4];
#pragma unroll
        for (int j = 0; j < 4; j++) sf[j] = (f32x4)0.0f;
#pragma unroll
        for (int st = 0; st < 2; st++) {
#pragma unroll
            for (int j = 0; j < 4; j++) {
                short8 kb2 = *(const short8*)&Klds[(j * 16 + l15) * 72 + st * 32 + quad * 8];
                sf[j] = __builtin_amdgcn_mfma_f32_16x16x32_bf16(qfrag[st], kb2, sf[j], 0, 0, 0);
            }
        }

        // bias via idx tile (symmetric layout); 0.125 folded into qe
        float sv[4][4];
#pragma unroll
        for (int j = 0; j < 4; j++) {
            const unsigned int iw = *(const unsigned int*)&Ilds[(j * 16 + l15) * IPAD + wave * 16 + quad * 4];
#pragma unroll
            for (int r = 0; r < 4; r++) {
                const int m = wave * 16 + quad * 4 + r;
                const int idx = (iw >> (8 * r)) & 0xFF;
                sv[r][j] = fmaf(sf[j][r], 0.125f, qe[m * NUMEMB + idx]);
            }
        }

        // online softmax per row — DPP reductions
        float alpha[4];
#pragma unroll
        for (int r = 0; r < 4; r++) {
            float vmax = fmaxf(fmaxf(sv[r][0], sv[r][1]), fmaxf(sv[r][2], sv[r][3]));
            vmax = red_max16(vmax);
            const float mnew = fmaxf(m_run[r], vmax);
            alpha[r] = __expf(m_run[r] - mnew);
            m_run[r] = mnew;
            float psum = 0.f;
#pragma unroll
            for (int j = 0; j < 4; j++) {
                const float p = __expf(sv[r][j] - mnew);
                sv[r][j] = p;
                psum += p;
            }
            psum = red_sum16(psum);
            l_run[r] = l_run[r] * alpha[r] + psum;
        }
#pragma unroll
        for (int j = 0; j < 4; j++) {
            f32x4 o = oacc[j];
#pragma unroll
            for (int r = 0; r < 4; r++) o[r] *= alpha[r];
            oacc[j] = o;
        }

        // P (bf16) -> LDS, XOR-swizzled; wave-private rows
#pragma unroll
        for (int r = 0; r < 4; r++) {
            const int m = wave * 16 + quad * 4 + r;
#pragma unroll
            for (int j = 0; j < 4; j++) {
                const int csw = (j * 16 + l15) ^ (quad << 4);
                Plds[m * 72 + csw] = f2bf_bits(sv[r][j]);
            }
        }

        // O += P @ V via MFMA
#pragma unroll
        for (int st = 0; st < 2; st++) {
            const int prow = wave * 16 + l15;
            const int pcsw = (st * 32 + quad * 8) ^ ((l15 >> 2) << 4);
            short8 pf = *(const short8*)&Plds[prow * 72 + pcsw];
#pragma unroll
            for (int j = 0; j < 4; j++) {
                const int d = j * 16 + l15;
                const int vsw = (st * 32 + quad * 8) ^ (((d >> 3) & 7) << 3);
                short8 vb = *(const short8*)&Vtlds[d * 72 + vsw];
                oacc[j] = __builtin_amdgcn_mfma_f32_16x16x32_bf16(pf, vb, oacc[j], 0, 0, 0);
            }
        }
    }

    if constexpr (SPLIT) {
        // write partials: (m,l) fp32 once per row; unnormalized O bf16
        const size_t rbase = (((size_t)(b * 2 + half) * Hn + h) * Ssz + qt * 64);
#pragma unroll
        for (int r = 0; r < 4; r++) {
            const int m = wave * 16 + quad * 4 + r;
            if (l15 == 0) {
                pml[(rbase + m) * 2]     = m_run[r];
                pml[(rbase + m) * 2 + 1] = l_run[r];
            }
#pragma unroll
            for (int j = 0; j < 4; j++)
                pO[(rbase + m) * DKsz + j * 16 + l15] = f2bf_bits(oacc[j][r]);
        }
    } else {
        __syncthreads();  // all Q reads done before overwriting out (Q aliases out)
#pragma unroll
        for (int r = 0; r < 4; r++) {
            const float inv = 1.0f / l_run[r];
            const int m = qt * 64 + wave * 16 + quad * 4 + r;
#pragma unroll
            for (int j = 0; j < 4; j++) {
                const int n = h * DKsz + j * 16 + l15;
                const float val = oacc[j][r] * inv;
                const size_t oidx = ((size_t)b * Ssz + m) * Dsz + n;
                if constexpr (QB) ((__hip_bfloat16*)out)[oidx] = __float2bfloat16(val);
                else              ((float*)out)[oidx] = val;
            }
        }
    }
}

template<bool SPLIT>
__device__ __forceinline__ void attn_dispatch(
    const void* Qw, const short* Ks, const short* Vs,
    const unsigned char* idxb, const void* emb, void* out,
    float* pml, unsigned short* pO, const int* flags,
    unsigned short* Klds, unsigned short* Vtlds, unsigned short* Plds,
    float* qe, unsigned char* Ilds)
{
    const bool qb = flags[0] != 0, eb = flags[3] != 0;
    if (qb) { if (eb) attn_body<true , true , SPLIT>(Qw, Ks, Vs, idxb, emb, out, pml, pO, Klds, Vtlds, Plds, qe, Ilds);
              else    attn_body<true , false, SPLIT>(Qw, Ks, Vs, idxb, emb, out, pml, pO, Klds, Vtlds, Plds, qe, Ilds); }
    else    { if (eb) attn_body<false, true , SPLIT>(Qw, Ks, Vs, idxb, emb, out, pml, pO, Klds, Vtlds, Plds, qe, Ilds);
              else    attn_body<false, false, SPLIT>(Qw, Ks, Vs, idxb, emb, out, pml, pO, Klds, Vtlds, Plds, qe, Ilds); }
}

__global__ __launch_bounds__(256) void attn_kernel(
    const void* Qw, const short* __restrict__ Ks, const short* __restrict__ Vs,
    const unsigned char* __restrict__ idxb, const void* __restrict__ emb, void* out,
    float* __restrict__ pml, unsigned short* __restrict__ pO,
    const int* __restrict__ flags, int split)
{
    __shared__ __align__(16) unsigned short Klds[64 * 72];
    __shared__ __align__(16) unsigned short Vtlds[64 * 72];
    __shared__ __align__(16) unsigned short Plds[64 * 72];
    __shared__ __align__(16) float qe[64 * NUMEMB];
    __shared__ __align__(16) unsigned char Ilds[64 * IPAD];

    if (split) attn_dispatch<true >(Qw, Ks, Vs, idxb, emb, out, pml, pO, flags, Klds, Vtlds, Plds, qe, Ilds);
    else       attn_dispatch<false>(Qw, Ks, Vs, idxb, emb, out, pml, pO, flags, Klds, Vtlds, Plds, qe, Ilds);
}

// ---------------- combine: merge the 2 K-half partials ---------------------
__global__ __launch_bounds__(256) void combine_kernel(
    const float* __restrict__ pml, const unsigned short* __restrict__ pO,
    void* out, const int* __restrict__ flags)
{
    const int qt = blockIdx.x, h = blockIdx.y, b = blockIdx.z;
    const int t = threadIdx.x;
    const int q = t >> 2, dg = t & 3;
    const int qg = qt * 64 + q;
    const size_t r1 = (((size_t)(b * 2 + 0) * Hn + h) * Ssz + qg);
    const size_t r2 = (((size_t)(b * 2 + 1) * Hn + h) * Ssz + qg);
    const float m1 = pml[r1 * 2], l1 = pml[r1 * 2 + 1];
    const float m2 = pml[r2 * 2], l2 = pml[r2 * 2 + 1];
    const float mm = fmaxf(m1, m2);
    const float w1 = __expf(m1 - mm), w2 = __expf(m2 - mm);
    const float inv = 1.0f / (w1 * l1 + w2 * l2);
    const bool obf = flags[0] != 0;
#pragma unroll
    for (int c = 0; c < 2; c++) {
        short8 o1 = *(const short8*)(pO + r1 * DKsz + dg * 16 + c * 8);
        short8 o2 = *(const short8*)(pO + r2 * DKsz + dg * 16 + c * 8);
        const size_t obase = ((size_t)b * Ssz + qg) * Dsz + h * DKsz + dg * 16 + c * 8;
        if (obf) {
#pragma unroll
            for (int i = 0; i < 8; i++) {
                const float v = (w1 * bfbits2f(o1[i]) + w2 * bfbits2f(o2[i])) * inv;
                ((__hip_bfloat16*)out)[obase + i] = __float2bfloat16(v);
            }
        } else {
            float8 v;
#pragma unroll
            for (int i = 0; i < 8; i++)
                v[i] = (w1 * bfbits2f(o1[i]) + w2 * bfbits2f(o2[i])) * inv;
            *(float8*)((float*)out + obase) = v;
        }
    }
}

extern "C" void kernel_launch(void* const* d_in, const int* in_sizes, int n_in,
                              void* d_out, int out_size, void* d_ws, size_t ws_size,
                              hipStream_t stream) {
    const void* query = d_in[0];
    const void* key   = d_in[1];
    const void* value = d_in[2];
    const void* tpos  = d_in[3];
    const void* Wq    = d_in[4];
    const void* bq    = d_in[5];
    const void* Wk    = d_in[6];
    const void* bk    = d_in[7];
    const void* Wv    = d_in[8];
    const void* bv    = d_in[9];
    const void* emb   = d_in[10];

    int*            flags = (int*)d_ws;
    unsigned char*  idxb  = (unsigned char*)d_ws + IDX_OFF;
    void*           Kw    = (char*)d_ws + K_OFF;
    void*           Vw    = (char*)d_ws + V_OFF;
    short*          Wbf   = (short*)((char*)d_ws + WBF_OFF);
    short*          Xbf   = (short*)((char*)d_ws + XBF_OFF);
    float*          pml   = (float*)((char*)d_ws + PML_OFF);
    unsigned short* pO    = (unsigned short*)((char*)d_ws + PO_OFF);
    void*           Qw    = d_out;   // Q staged in d_out

    const bool tierA = ws_size >= WS_TIER_A;
    const bool tierB = !tierA && ws_size >= WS_TIER_B;

    detect_kernel<<<4, 64, 0, stream>>>(
        (const unsigned int*)query, (const unsigned int*)tpos,
        (const unsigned int*)Wq, (const unsigned int*)emb, flags);

    if (tierA)
        conv_kernel<<<5472, 256, 0, stream>>>(query, key, value, Wq, Wk, Wv, flags, Xbf, Wbf, 1);
    else if (tierB)
        conv_kernel<<<864, 256, 0, stream>>>(query, key, value, Wq, Wk, Wv, flags, Xbf, Wbf, 0);

    idx_kernel<<<dim3(16, 16, Bsz), 256, 0, stream>>>(tpos, flags, idxb);

    if (tierA)
        proj_kernel<<<dim3(64, 6, 3), 256, 0, stream>>>(
            Xbf, Xbf + NXz, Xbf + 2 * NXz,
            Wbf, bq, Wbf + NWz, bk, Wbf + 2 * NWz, bv,
            Qw, Kw, Vw, flags, 1, 1);
    else if (tierB)
        proj_kernel<<<dim3(64, 6, 3), 256, 0, stream>>>(
            query, key, value,
            Wbf, bq, Wbf + NWz, bk, Wbf + 2 * NWz, bv,
            Qw, Kw, Vw, flags, 0, 1);
    else
        proj_kernel<<<dim3(64, 6, 3), 256, 0, stream>>>(
            query, key, value, Wq, bq, Wk, bk, Wv, bv,
            Qw, Kw, Vw, flags, 0, 0);

    if (tierA) {
        // K-split x2 (partials overlay dead Wbf/Xbf region) + combine
        attn_kernel<<<dim3(16, Hn, Bsz * 2), 256, 0, stream>>>(
            Qw, (const short*)Kw, (const short*)Vw, idxb, emb, d_out, pml, pO, flags, 1);
        combine_kernel<<<dim3(16, Hn, Bsz), 256, 0, stream>>>(pml, pO, d_out, flags);
    } else {
        attn_kernel<<<dim3(16, Hn, Bsz), 256, 0, stream>>>(
            Qw, (const short*)Kw, (const short*)Vw, idxb, emb, d_out, pml, pO, flags, 0);
    }
}

// Round 10
// 230.588 us; speedup vs baseline: 1.0083x; 1.0083x over previous
//
#include <hip/hip_runtime.h>
#include <hip/hip_bf16.h>

#define Bsz 4
#define Ssz 1024
#define Dsz 768
#define Hn 12
#define DKsz 64
#define NUMEMB 10

// d_ws layout (bytes)
#define IDX_OFF 64
#define K_OFF   4194368          // IDX_OFF + 4*1024*1024
#define V_OFF   10485824         // K_OFF + 4*1024*768*2
#define WBF_OFF 16777280         // V_OFF + 4*1024*768*2
#define XBF_OFF 20316224         // WBF_OFF + 3*768*768*2
#define VT_OFF  20316224         // V^T overlays Xbf (proj done before vt/attn)
#define WS_TIER_B 20316224ULL
#define WS_TIER_A 39190592ULL

#define NXz 3145728              // elems per X tensor
#define NWz 589824               // elems per W tensor

#define IPAD 80                  // idx tile row stride for fallback path (bytes)

typedef __attribute__((ext_vector_type(8))) short short8;
typedef __attribute__((ext_vector_type(8))) float float8;
typedef __attribute__((ext_vector_type(4))) float f32x4;
typedef __attribute__((ext_vector_type(4))) unsigned int u32x4;

__device__ __forceinline__ float bfbits2f(short u) {
    union { unsigned int i; float f; } v;
    v.i = ((unsigned int)(unsigned short)u) << 16;
    return v.f;
}
__device__ __forceinline__ unsigned short f2bf_bits(float f) {
    __hip_bfloat16 h = __float2bfloat16(f);
    return *reinterpret_cast<unsigned short*>(&h);
}

// async global->LDS DMA, 16B per lane; LDS dest = wave-uniform base + lane*16
__device__ __forceinline__ void dma16(const void* g, void* l) {
    __builtin_amdgcn_global_load_lds(
        (const __attribute__((address_space(1))) unsigned int*)g,
        (__attribute__((address_space(3))) unsigned int*)l, 16, 0, 0);
}

// DPP lane permute within 16-lane rows (VALU pipe)
template<int CTRL>
__device__ __forceinline__ float dppf(float x) {
    int xi = __float_as_int(x);
    int r = __builtin_amdgcn_update_dpp(xi, xi, CTRL, 0xF, 0xF, true);
    return __int_as_float(r);
}
__device__ __forceinline__ float red_max16(float v) {
    v = fmaxf(v, dppf<0xB1>(v));
    v = fmaxf(v, dppf<0x4E>(v));
    v = fmaxf(v, dppf<0x124>(v));
    v = fmaxf(v, dppf<0x128>(v));
    return v;
}
__device__ __forceinline__ float red_sum16(float v) {
    v += dppf<0xB1>(v);
    v += dppf<0x4E>(v);
    v += dppf<0x124>(v);
    v += dppf<0x128>(v);
    return v;
}

template<bool BF16>
__device__ __forceinline__ float loadf(const void* base, size_t idx) {
    if constexpr (BF16) return __bfloat162float(((const __hip_bfloat16*)base)[idx]);
    else return ((const float*)base)[idx];
}
template<bool BF16>
__device__ __forceinline__ short8 load8bf(const void* base, size_t idx) {
    if constexpr (BF16) {
        return *(const short8*)((const short*)base + idx);
    } else {
        float8 f = *(const float8*)((const float*)base + idx);
        short8 r;
#pragma unroll
        for (int i = 0; i < 8; i++) r[i] = (short)f2bf_bits(f[i]);
        return r;
    }
}
template<bool BF16>
__device__ __forceinline__ float8 load8f(const void* base, size_t idx) {
    if constexpr (BF16) {
        short8 s = *(const short8*)((const short*)base + idx);
        float8 f;
#pragma unroll
        for (int i = 0; i < 8; i++) f[i] = bfbits2f(s[i]);
        return f;
    } else {
        return *(const float8*)((const float*)base + idx);
    }
}

// ---------------- dtype detector ------------------------------------------
__global__ __launch_bounds__(64) void detect_kernel(
    const unsigned int* __restrict__ q, const unsigned int* __restrict__ p,
    const unsigned int* __restrict__ w, const unsigned int* __restrict__ e,
    int* __restrict__ flags)
{
    const int which = blockIdx.x;
    const unsigned int* ptr = (which == 0) ? q : ((which == 1) ? p : ((which == 2) ? w : e));
    const int n = (which == 3) ? 320 : ((which == 1) ? 4096 : 1024);
    int cnt = 0;
    for (int i = threadIdx.x; i < n; i += 64) {
        const unsigned int ex = (ptr[i] >> 7) & 0xFF;
        cnt += (ex >= 110 && ex <= 145) ? 1 : 0;
    }
#pragma unroll
    for (int off = 1; off < 64; off <<= 1) cnt += __shfl_xor(cnt, off, 64);
    if (threadIdx.x == 0) flags[which] = (2 * cnt > n) ? 1 : 0;
}

// ---------------- one-time bf16 canonicalization of X / W ------------------
__global__ __launch_bounds__(256) void conv_kernel(
    const void* __restrict__ X0, const void* __restrict__ X1, const void* __restrict__ X2,
    const void* __restrict__ W0, const void* __restrict__ W1, const void* __restrict__ W2,
    const int* __restrict__ flags, short* __restrict__ Xbf, short* __restrict__ Wbf,
    int doX)
{
    const long t = (long)blockIdx.x * 256 + threadIdx.x;
    const bool xb = flags[0] != 0, wb = flags[2] != 0;
    if (doX) {
        const long i8 = t * 8;
        if (i8 < (long)3 * NXz) {
            const int z = (int)(i8 / NXz);
            const long off = i8 - (long)z * NXz;
            const void* X = (z == 0) ? X0 : ((z == 1) ? X1 : X2);
            short8 v = xb ? load8bf<true>(X, off) : load8bf<false>(X, off);
            *(short8*)(Xbf + i8) = v;
        } else {
            const long j = i8 - (long)3 * NXz;
            const int z = (int)(j / NWz);
            const long off = j - (long)z * NWz;
            const void* W = (z == 0) ? W0 : ((z == 1) ? W1 : W2);
            short8 v = wb ? load8bf<true>(W, off) : load8bf<false>(W, off);
            *(short8*)(Wbf + j) = v;
        }
    } else {
        const long j = t * 8;
        const int z = (int)(j / NWz);
        const long off = j - (long)z * NWz;
        const void* W = (z == 0) ? W0 : ((z == 1) ? W1 : W2);
        short8 v = wb ? load8bf<true>(W, off) : load8bf<false>(W, off);
        *(short8*)(Wbf + j) = v;
    }
}

// ---------------- idx precompute: idx[b][i][j], uint8 (bitwise symmetric) ---
template<bool PB>
__device__ __forceinline__ void idx_body(
    const void* pos, unsigned char* __restrict__ idxb, float* qp, float* kp)
{
    const int kt = blockIdx.x, qt = blockIdx.y, b = blockIdx.z;
    const int t = threadIdx.x;
    if (t < 128) {
        const int row = t >> 1, c = t & 1;
        qp[t] = loadf<PB>(pos, ((size_t)b * Ssz + qt * 64 + row) * 2 + c);
    } else {
        const int t2 = t - 128;
        const int row = t2 >> 1, c = t2 & 1;
        kp[t2] = loadf<PB>(pos, ((size_t)b * Ssz + kt * 64 + row) * 2 + c);
    }
    __syncthreads();

    const int r = t >> 2, cc = t & 3;
    const int q = qt * 64 + r;
    const float qx = qp[r * 2], qy = qp[r * 2 + 1];
    const float MAXD = 141421.35623730951f;  // fp32(100000*sqrt(2))
    const int k0 = kt * 64 + cc * 16;
    unsigned int w[4];
#pragma unroll
    for (int g = 0; g < 4; g++) {
        unsigned int acc = 0;
#pragma unroll
        for (int u = 0; u < 4; u++) {
            const int kl = cc * 16 + g * 4 + u;
            const float kx = kp[kl * 2], ky = kp[kl * 2 + 1];
            const float dx = __fsub_rn(qx, kx);
            const float dy = __fsub_rn(qy, ky);
            const float ss = __fadd_rn(__fmul_rn(dx, dx), __fmul_rn(dy, dy));
            const float dist = __fdiv_rn(sqrtf(ss), MAXD);
            const float d9 = __fmul_rn(dist, 9.0f);
            int idx = (int)rintf(d9);
            idx = idx < 0 ? 0 : (idx > NUMEMB - 1 ? NUMEMB - 1 : idx);
            acc |= ((unsigned int)idx) << (8 * u);
        }
        w[g] = acc;
    }
    u32x4 v; v[0] = w[0]; v[1] = w[1]; v[2] = w[2]; v[3] = w[3];
    *(u32x4*)(idxb + ((size_t)(b * Ssz + q)) * Ssz + k0) = v;
}

__global__ __launch_bounds__(256) void idx_kernel(
    const void* pos, const int* __restrict__ flags, unsigned char* __restrict__ idxb)
{
    __shared__ __align__(16) float qp[128];
    __shared__ __align__(16) float kp[128];
    if (flags[1] != 0) idx_body<true >(pos, idxb, qp, kp);
    else               idx_body<false>(pos, idxb, qp, kp);
}

// ---------------- Projection GEMM: Y = X @ W^T + b -------------------------
template<bool XB, bool WB>
__device__ __forceinline__ void proj_body(
    const void* X, const void* W, const void* bias, bool biasbf, void* Y, bool ybf,
    int bx, int by, short* As, short* Bs)
{
    const int tid  = threadIdx.x;
    const int wave = tid >> 6;
    const int lane = tid & 63;
    const int l15  = lane & 15;
    const int quad = lane >> 4;
    const int wm = wave & 1;
    const int wn = wave >> 1;
    const int m0 = bx * 64;
    const int n0 = by * 128;

    f32x4 acc[2][4];
#pragma unroll
    for (int i = 0; i < 2; i++)
#pragma unroll
        for (int j = 0; j < 4; j++) acc[i][j] = (f32x4)0.0f;

    const int r0 = tid >> 3;
    const int cc = tid & 7;

    short8 pa0 = load8bf<XB>(X, (size_t)(m0 + r0)      * Dsz + cc * 8);
    short8 pa1 = load8bf<XB>(X, (size_t)(m0 + 32 + r0) * Dsz + cc * 8);
    short8 pb0 = load8bf<WB>(W, (size_t)(n0 + r0)      * Dsz + cc * 8);
    short8 pb1 = load8bf<WB>(W, (size_t)(n0 + 32 + r0) * Dsz + cc * 8);
    short8 pb2 = load8bf<WB>(W, (size_t)(n0 + 64 + r0) * Dsz + cc * 8);
    short8 pb3 = load8bf<WB>(W, (size_t)(n0 + 96 + r0) * Dsz + cc * 8);

    for (int kk = 0; kk < Dsz; kk += 64) {
        __syncthreads();
        *(short8*)&As[(r0)      * 72 + cc * 8] = pa0;
        *(short8*)&As[(32 + r0) * 72 + cc * 8] = pa1;
        *(short8*)&Bs[(r0)      * 72 + cc * 8] = pb0;
        *(short8*)&Bs[(32 + r0) * 72 + cc * 8] = pb1;
        *(short8*)&Bs[(64 + r0) * 72 + cc * 8] = pb2;
        *(short8*)&Bs[(96 + r0) * 72 + cc * 8] = pb3;
        __syncthreads();

        if (kk + 64 < Dsz) {
            const int k2 = kk + 64 + cc * 8;
            pa0 = load8bf<XB>(X, (size_t)(m0 + r0)      * Dsz + k2);
            pa1 = load8bf<XB>(X, (size_t)(m0 + 32 + r0) * Dsz + k2);
            pb0 = load8bf<WB>(W, (size_t)(n0 + r0)      * Dsz + k2);
            pb1 = load8bf<WB>(W, (size_t)(n0 + 32 + r0) * Dsz + k2);
            pb2 = load8bf<WB>(W, (size_t)(n0 + 64 + r0) * Dsz + k2);
            pb3 = load8bf<WB>(W, (size_t)(n0 + 96 + r0) * Dsz + k2);
        }

#pragma unroll
        for (int st = 0; st < 2; st++) {
            short8 af[2], bf[4];
#pragma unroll
            for (int i = 0; i < 2; i++)
                af[i] = *(const short8*)&As[(wm * 32 + i * 16 + l15) * 72 + st * 32 + quad * 8];
#pragma unroll
            for (int j = 0; j < 4; j++)
                bf[j] = *(const short8*)&Bs[(wn * 64 + j * 16 + l15) * 72 + st * 32 + quad * 8];
#pragma unroll
            for (int i = 0; i < 2; i++)
#pragma unroll
                for (int j = 0; j < 4; j++)
                    acc[i][j] = __builtin_amdgcn_mfma_f32_16x16x32_bf16(af[i], bf[j], acc[i][j], 0, 0, 0);
        }
    }

#pragma unroll
    for (int j = 0; j < 4; j++) {
        const int n = n0 + wn * 64 + j * 16 + l15;
        const float bv_ = biasbf ? loadf<true>(bias, n) : loadf<false>(bias, n);
#pragma unroll
        for (int i = 0; i < 2; i++) {
#pragma unroll
            for (int r = 0; r < 4; r++) {
                const int m = m0 + wm * 32 + i * 16 + quad * 4 + r;
                const float val = acc[i][j][r] + bv_;
                if (ybf) ((__hip_bfloat16*)Y)[(size_t)m * Dsz + n] = __float2bfloat16(val);
                else     ((float*)Y)[(size_t)m * Dsz + n] = val;
            }
        }
    }
}

__global__ __launch_bounds__(256) void proj_kernel(
    const void* X0, const void* X1, const void* X2,
    const void* Wq, const void* bq, const void* Wk, const void* bk,
    const void* Wv, const void* bv,
    void* Qw, void* Kw, void* Vw, const int* __restrict__ flags,
    int fx, int fw)
{
    __shared__ __align__(16) short As[64 * 72];
    __shared__ __align__(16) short Bs[128 * 72];
    const int z = blockIdx.z;
    const void* X = (z == 0) ? X0 : ((z == 1) ? X1 : X2);
    const void* W = (z == 0) ? Wq : ((z == 1) ? Wk : Wv);
    const void* B = (z == 0) ? bq : ((z == 1) ? bk : bv);
    void* Y = (z == 0) ? Qw : ((z == 1) ? Kw : Vw);
    const bool xb = fx || flags[0] != 0;
    const bool wb = fw || flags[2] != 0;
    const bool biasbf = flags[2] != 0;
    const bool ybf = (flags[0] != 0) || (z != 0);
    if (xb) { if (wb) proj_body<true , true >(X, W, B, biasbf, Y, ybf, blockIdx.x, blockIdx.y, As, Bs);
              else    proj_body<true , false>(X, W, B, biasbf, Y, ybf, blockIdx.x, blockIdx.y, As, Bs); }
    else    { if (wb) proj_body<false, true >(X, W, B, biasbf, Y, ybf, blockIdx.x, blockIdx.y, As, Bs);
              else    proj_body<false, false>(X, W, B, biasbf, Y, ybf, blockIdx.x, blockIdx.y, As, Bs); }
}

// ---------------- V transpose: Vt[(b*12+h)*64+d][s] = V[b][s][h*64+d] -------
__global__ __launch_bounds__(256) void vt_kernel(
    const short* __restrict__ Vw, short* __restrict__ Vtg)
{
    __shared__ __align__(16) unsigned short t[64 * 72];
    const int stile = blockIdx.x, h = blockIdx.y, b = blockIdx.z;
    const int tid = threadIdx.x;
    const int vp = tid >> 3, chunk = tid & 7;
    const size_t base = ((size_t)b * Ssz + stile * 64) * Dsz + h * DKsz;
    short8 pv0 = *(const short8*)(Vw + base + (size_t)(2 * vp)     * Dsz + chunk * 8);
    short8 pv1 = *(const short8*)(Vw + base + (size_t)(2 * vp + 1) * Dsz + chunk * 8);
#pragma unroll
    for (int i = 0; i < 8; i++) {
        const unsigned int dw = (unsigned int)(unsigned short)pv0[i]
                              | ((unsigned int)(unsigned short)pv1[i] << 16);
        *(unsigned int*)&t[(chunk * 8 + i) * 72 + 2 * vp] = dw;
    }
    __syncthreads();
    const int drow = tid >> 2, c2 = tid & 3;
#pragma unroll
    for (int cc = 0; cc < 2; cc++) {
        const int c = c2 + cc * 4;
        short8 o = *(const short8*)&t[drow * 72 + c * 8];
        *(short8*)(Vtg + (((size_t)(b * Hn + h) * 64 + drow) * Ssz) + stile * 64 + c * 8) = o;
    }
}

// ---------------- attention: DMA-staged (tier A) ----------------------------
// K/Vt/idx tiles via global_load_lds into double buffers; read-side XOR
// swizzle baked into the GLOBAL addresses (LDS stays lane-linear).
template<bool QB, bool EB>
__device__ __forceinline__ void attn_dma_body(
    const void* Qw, const short* __restrict__ Ks, const short* __restrict__ Vtg,
    const unsigned char* __restrict__ idxb, const void* __restrict__ emb, void* out,
    short* Kl, short* Vtl, unsigned char* Il, unsigned short* Pl, float* qe)
{
    const int qt = blockIdx.x, h = blockIdx.y, b = blockIdx.z;
    const int tid  = threadIdx.x;
    const int wave = tid >> 6;
    const int lane = tid & 63;
    const int l15  = lane & 15;
    const int quad = lane >> 4;

    // swizzled per-lane global chunk indices (read side undoes the swizzle)
    const int cK = (lane & 7) ^ ((lane >> 3) & 7);
    const int cI = (lane & 3) ^ ((lane >> 2) & 3);
    const int krow = lane >> 3;        // 0..7 within a wave's 8-row slab
    const int irow = lane >> 2;        // 0..15 within a wave's 16-row slab

    // qe[row][e] = 0.125 * sum_d Q[b,qrow,h*64+d] * emb[e][d]
    for (int p = tid; p < 64 * NUMEMB; p += 256) {
        const int row = p / NUMEMB, e = p - row * NUMEMB;
        const size_t qoff = ((size_t)b * Ssz + qt * 64 + row) * Dsz + h * DKsz;
        float s = 0.f;
#pragma unroll
        for (int c = 0; c < 8; c++) {
            short8 qv = load8bf<QB>(Qw, qoff + c * 8);
            float8 ef = load8f<EB>(emb, (size_t)e * DKsz + c * 8);
#pragma unroll
            for (int i = 0; i < 8; i++) s += bfbits2f(qv[i]) * ef[i];
        }
        qe[p] = s * 0.125f;
    }

    short8 qfrag[2];
    {
        const size_t qbase = ((size_t)b * Ssz + qt * 64 + wave * 16 + l15) * Dsz + h * DKsz;
        qfrag[0] = load8bf<QB>(Qw, qbase + quad * 8);
        qfrag[1] = load8bf<QB>(Qw, qbase + 32 + quad * 8);
    }

    float m_run[4], l_run[4];
    f32x4 oacc[4];
#pragma unroll
    for (int r = 0; r < 4; r++) { m_run[r] = -1e30f; l_run[r] = 0.f; }
#pragma unroll
    for (int j = 0; j < 4; j++) oacc[j] = (f32x4)0.0f;

    // DMA issue for iteration `it` into buffer `buf`
    auto issue = [&](int it, int buf) {
        short* kb = Kl + buf * 4096;
        short* vb = Vtl + buf * 4096;
        unsigned char* ib = Il + buf * 4096;
#pragma unroll
        for (int hh = 0; hh < 2; hh++) {
            const size_t gk = ((size_t)(b * Ssz + it * 64 + hh * 32 + wave * 8 + krow)) * Dsz + h * DKsz + cK * 8;
            dma16(Ks + gk, (char*)kb + hh * 4096 + wave * 1024);
            const size_t gv = (((size_t)(b * Hn + h) * 64) + hh * 32 + wave * 8 + krow) * Ssz + it * 64 + cK * 8;
            dma16(Vtg + gv, (char*)vb + hh * 4096 + wave * 1024);
        }
        const size_t gi = ((size_t)(b * Ssz + it * 64 + wave * 16 + irow)) * Ssz + qt * 64 + cI * 16;
        dma16(idxb + gi, (char*)ib + wave * 1024);
    };

    issue(0, 0);

    for (int it = 0; it < 16; it++) {
        const int cur = it & 1;
        __syncthreads();   // drains DMA (buf cur ready) + all waves done reading buf nxt
        if (it + 1 < 16) issue(it + 1, cur ^ 1);

        const short* kb = Kl + cur * 4096;
        const short* vb = Vtl + cur * 4096;
        const unsigned char* ib = Il + cur * 4096;

        // S = Q K^T via MFMA (phys chunk = logical ^ (row&7))
        f32x4 sf[4];
#pragma unroll
        for (int j = 0; j < 4; j++) sf[j] = (f32x4)0.0f;
#pragma unroll
        for (int st = 0; st < 2; st++) {
#pragma unroll
            for (int j = 0; j < 4; j++) {
                const int pc = (st * 4 + quad) ^ (l15 & 7);
                short8 kf = *(const short8*)(kb + (j * 16 + l15) * 64 + pc * 8);
                sf[j] = __builtin_amdgcn_mfma_f32_16x16x32_bf16(qfrag[st], kf, sf[j], 0, 0, 0);
            }
        }

        // bias via idx tile (k-row, q-col; symmetric matrix)
        float sv[4][4];
#pragma unroll
        for (int j = 0; j < 4; j++) {
            const int row = j * 16 + l15;
            const int pd = ((wave ^ (row & 3)) << 2) | quad;
            const unsigned int iw = *(const unsigned int*)(ib + row * 64 + pd * 4);
#pragma unroll
            for (int r = 0; r < 4; r++) {
                const int m = wave * 16 + quad * 4 + r;
                const int idx = (iw >> (8 * r)) & 0xFF;
                sv[r][j] = fmaf(sf[j][r], 0.125f, qe[m * NUMEMB + idx]);
            }
        }

        // online softmax per row — DPP reductions
        float alpha[4];
#pragma unroll
        for (int r = 0; r < 4; r++) {
            float vmax = fmaxf(fmaxf(sv[r][0], sv[r][1]), fmaxf(sv[r][2], sv[r][3]));
            vmax = red_max16(vmax);
            const float mnew = fmaxf(m_run[r], vmax);
            alpha[r] = __expf(m_run[r] - mnew);
            m_run[r] = mnew;
            float psum = 0.f;
#pragma unroll
            for (int j = 0; j < 4; j++) {
                const float p = __expf(sv[r][j] - mnew);
                sv[r][j] = p;
                psum += p;
            }
            psum = red_sum16(psum);
            l_run[r] = l_run[r] * alpha[r] + psum;
        }
#pragma unroll
        for (int j = 0; j < 4; j++) {
            f32x4 o = oacc[j];
#pragma unroll
            for (int r = 0; r < 4; r++) o[r] *= alpha[r];
            oacc[j] = o;
        }

        // P (bf16) -> LDS, XOR-swizzled; wave-private rows (no barrier)
#pragma unroll
        for (int r = 0; r < 4; r++) {
            const int m = wave * 16 + quad * 4 + r;
#pragma unroll
            for (int j = 0; j < 4; j++) {
                const int csw = (j * 16 + l15) ^ (quad << 4);
                Pl[m * 72 + csw] = f2bf_bits(sv[r][j]);
            }
        }

        // O += P @ V via MFMA
#pragma unroll
        for (int st = 0; st < 2; st++) {
            const int prow = wave * 16 + l15;
            const int pcsw = (st * 32 + quad * 8) ^ ((l15 >> 2) << 4);
            short8 pf = *(const short8*)&Pl[prow * 72 + pcsw];
#pragma unroll
            for (int j = 0; j < 4; j++) {
                const int d = j * 16 + l15;
                const int pc = (st * 4 + quad) ^ (d & 7);
                short8 vf = *(const short8*)(vb + d * 64 + pc * 8);
                oacc[j] = __builtin_amdgcn_mfma_f32_16x16x32_bf16(pf, vf, oacc[j], 0, 0, 0);
            }
        }
    }

    __syncthreads();  // all Q reads of this block's region done before overwrite

#pragma unroll
    for (int r = 0; r < 4; r++) {
        const float inv = 1.0f / l_run[r];
        const int m = qt * 64 + wave * 16 + quad * 4 + r;
#pragma unroll
        for (int j = 0; j < 4; j++) {
            const int n = h * DKsz + j * 16 + l15;
            const float val = oacc[j][r] * inv;
            const size_t oidx = ((size_t)b * Ssz + m) * Dsz + n;
            if constexpr (QB) ((__hip_bfloat16*)out)[oidx] = __float2bfloat16(val);
            else              ((float*)out)[oidx] = val;
        }
    }
}

__global__ __launch_bounds__(256) void attn_dma_kernel(
    const void* Qw, const short* __restrict__ Ks, const short* __restrict__ Vtg,
    const unsigned char* __restrict__ idxb, const void* __restrict__ emb, void* out,
    const int* __restrict__ flags)
{
    __shared__ __align__(16) short Kl[2 * 4096];
    __shared__ __align__(16) short Vtl[2 * 4096];
    __shared__ __align__(16) unsigned char Il[2 * 4096];
    __shared__ __align__(16) unsigned short Pl[64 * 72];
    __shared__ __align__(16) float qe[64 * NUMEMB];

    const bool qb = flags[0] != 0, eb = flags[3] != 0;
    if (qb) { if (eb) attn_dma_body<true , true >(Qw, Ks, Vtg, idxb, emb, out, Kl, Vtl, Il, Pl, qe);
              else    attn_dma_body<true , false>(Qw, Ks, Vtg, idxb, emb, out, Kl, Vtl, Il, Pl, qe); }
    else    { if (eb) attn_dma_body<false, true >(Qw, Ks, Vtg, idxb, emb, out, Kl, Vtl, Il, Pl, qe);
              else    attn_dma_body<false, false>(Qw, Ks, Vtg, idxb, emb, out, Kl, Vtl, Il, Pl, qe); }
}

// ---------------- attention: register-staged fallback (R8 body) -------------
template<bool QB, bool EB>
__device__ __forceinline__ void attn_reg_body(
    const void* Qw, const short* __restrict__ Ks, const short* __restrict__ Vs,
    const unsigned char* __restrict__ idxb, const void* __restrict__ emb, void* out,
    unsigned short* Klds, unsigned short* Vtlds, unsigned short* Plds,
    float* qe, unsigned char* Ilds)
{
    const int qt = blockIdx.x, h = blockIdx.y, b = blockIdx.z;
    const int tid  = threadIdx.x;
    const int wave = tid >> 6;
    const int lane = tid & 63;
    const int l15  = lane & 15;
    const int quad = lane >> 4;

    for (int p = tid; p < 64 * NUMEMB; p += 256) {
        const int row = p / NUMEMB, e = p - row * NUMEMB;
        const size_t qoff = ((size_t)b * Ssz + qt * 64 + row) * Dsz + h * DKsz;
        float s = 0.f;
#pragma unroll
        for (int c = 0; c < 8; c++) {
            short8 qv = load8bf<QB>(Qw, qoff + c * 8);
            float8 ef = load8f<EB>(emb, (size_t)e * DKsz + c * 8);
#pragma unroll
            for (int i = 0; i < 8; i++) s += bfbits2f(qv[i]) * ef[i];
        }
        qe[p] = s * 0.125f;
    }

    short8 qfrag[2];
    {
        const size_t qbase = ((size_t)b * Ssz + qt * 64 + wave * 16 + l15) * Dsz + h * DKsz;
        qfrag[0] = load8bf<QB>(Qw, qbase + quad * 8);
        qfrag[1] = load8bf<QB>(Qw, qbase + 32 + quad * 8);
    }

    float m_run[4], l_run[4];
    f32x4 oacc[4];
#pragma unroll
    for (int r = 0; r < 4; r++) { m_run[r] = -1e30f; l_run[r] = 0.f; }
#pragma unroll
    for (int j = 0; j < 4; j++) oacc[j] = (f32x4)0.0f;

    const int srow = tid >> 3, schk = tid & 7;
    const int vp   = tid >> 3;
    const int irow = tid >> 2, ichk = tid & 3;

    short8 pk0, pk1, pv0, pv1;
    u32x4 pidx;
    {
        pk0 = *(const short8*)(Ks + ((size_t)b * Ssz + srow)       * Dsz + h * DKsz + schk * 8);
        pk1 = *(const short8*)(Ks + ((size_t)b * Ssz + 32 + srow)  * Dsz + h * DKsz + schk * 8);
        pv0 = *(const short8*)(Vs + ((size_t)b * Ssz + 2 * vp)     * Dsz + h * DKsz + schk * 8);
        pv1 = *(const short8*)(Vs + ((size_t)b * Ssz + 2 * vp + 1) * Dsz + h * DKsz + schk * 8);
        pidx = *(const u32x4*)(idxb + ((size_t)(b * Ssz + irow)) * Ssz + qt * 64 + ichk * 16);
    }

    for (int it = 0; it < 16; it++) {
        __syncthreads();
        *(short8*)&Klds[(srow)      * 72 + schk * 8] = pk0;
        *(short8*)&Klds[(32 + srow) * 72 + schk * 8] = pk1;
        {
            const int ssw = (2 * vp) ^ (schk << 3);
#pragma unroll
            for (int i = 0; i < 8; i++) {
                const unsigned int dw = (unsigned int)(unsigned short)pv0[i]
                                      | ((unsigned int)(unsigned short)pv1[i] << 16);
                *(unsigned int*)&Vtlds[(schk * 8 + i) * 72 + ssw] = dw;
            }
        }
        *(u32x4*)&Ilds[irow * IPAD + ichk * 16] = pidx;
        __syncthreads();

        if (it + 1 < 16) {
            const size_t kb = ((size_t)b * Ssz + (it + 1) * 64) * Dsz + h * DKsz;
            pk0 = *(const short8*)(Ks + kb + (size_t)srow * Dsz + schk * 8);
            pk1 = *(const short8*)(Ks + kb + (size_t)(32 + srow) * Dsz + schk * 8);
            pv0 = *(const short8*)(Vs + kb + (size_t)(2 * vp) * Dsz + schk * 8);
            pv1 = *(const short8*)(Vs + kb + (size_t)(2 * vp + 1) * Dsz + schk * 8);
            pidx = *(const u32x4*)(idxb + ((size_t)(b * Ssz + (it + 1) * 64 + irow)) * Ssz + qt * 64 + ichk * 16);
        }

        f32x4 sf[4];
#pragma unroll
        for (int j = 0; j < 4; j++) sf[j] = (f32x4)0.0f;
#pragma unroll
        for (int st = 0; st < 2; st++) {
#pragma unroll
            for (int j = 0; j < 4; j++) {
                short8 kb2 = *(const short8*)&Klds[(j * 16 + l15) * 72 + st * 32 + quad * 8];
                sf[j] = __builtin_amdgcn_mfma_f32_16x16x32_bf16(qfrag[st], kb2, sf[j], 0, 0, 0);
            }
        }

        float sv[4][4];
#pragma unroll
        for (int j = 0; j < 4; j++) {
            const unsigned int iw = *(const unsigned int*)&Ilds[(j * 16 + l15) * IPAD + wave * 16 + quad * 4];
#pragma unroll
            for (int r = 0; r < 4; r++) {
                const int m = wave * 16 + quad * 4 + r;
                const int idx = (iw >> (8 * r)) & 0xFF;
                sv[r][j] = fmaf(sf[j][r], 0.125f, qe[m * NUMEMB + idx]);
            }
        }

        float alpha[4];
#pragma unroll
        for (int r = 0; r < 4; r++) {
            float vmax = fmaxf(fmaxf(sv[r][0], sv[r][1]), fmaxf(sv[r][2], sv[r][3]));
            vmax = red_max16(vmax);
            const float mnew = fmaxf(m_run[r], vmax);
            alpha[r] = __expf(m_run[r] - mnew);
            m_run[r] = mnew;
            float psum = 0.f;
#pragma unroll
            for (int j = 0; j < 4; j++) {
                const float p = __expf(sv[r][j] - mnew);
                sv[r][j] = p;
                psum += p;
            }
            psum = red_sum16(psum);
            l_run[r] = l_run[r] * alpha[r] + psum;
        }
#pragma unroll
        for (int j = 0; j < 4; j++) {
            f32x4 o = oacc[j];
#pragma unroll
            for (int r = 0; r < 4; r++) o[r] *= alpha[r];
            oacc[j] = o;
        }

#pragma unroll
        for (int r = 0; r < 4; r++) {
            const int m = wave * 16 + quad * 4 + r;
#pragma unroll
            for (int j = 0; j < 4; j++) {
                const int csw = (j * 16 + l15) ^ (quad << 4);
                Plds[m * 72 + csw] = f2bf_bits(sv[r][j]);
            }
        }

#pragma unroll
        for (int st = 0; st < 2; st++) {
            const int prow = wave * 16 + l15;
            const int pcsw = (st * 32 + quad * 8) ^ ((l15 >> 2) << 4);
            short8 pf = *(const short8*)&Plds[prow * 72 + pcsw];
#pragma unroll
            for (int j = 0; j < 4; j++) {
                const int d = j * 16 + l15;
                const int vsw = (st * 32 + quad * 8) ^ (((d >> 3) & 7) << 3);
                short8 vbf = *(const short8*)&Vtlds[d * 72 + vsw];
                oacc[j] = __builtin_amdgcn_mfma_f32_16x16x32_bf16(pf, vbf, oacc[j], 0, 0, 0);
            }
        }
    }

    __syncthreads();

#pragma unroll
    for (int r = 0; r < 4; r++) {
        const float inv = 1.0f / l_run[r];
        const int m = qt * 64 + wave * 16 + quad * 4 + r;
#pragma unroll
        for (int j = 0; j < 4; j++) {
            const int n = h * DKsz + j * 16 + l15;
            const float val = oacc[j][r] * inv;
            const size_t oidx = ((size_t)b * Ssz + m) * Dsz + n;
            if constexpr (QB) ((__hip_bfloat16*)out)[oidx] = __float2bfloat16(val);
            else              ((float*)out)[oidx] = val;
        }
    }
}

__global__ __launch_bounds__(256) void attn_reg_kernel(
    const void* Qw, const short* __restrict__ Ks, const short* __restrict__ Vs,
    const unsigned char* __restrict__ idxb, const void* __restrict__ emb, void* out,
    const int* __restrict__ flags)
{
    __shared__ __align__(16) unsigned short Klds[64 * 72];
    __shared__ __align__(16) unsigned short Vtlds[64 * 72];
    __shared__ __align__(16) unsigned short Plds[64 * 72];
    __shared__ __align__(16) float qe[64 * NUMEMB];
    __shared__ __align__(16) unsigned char Ilds[64 * IPAD];

    const bool qb = flags[0] != 0, eb = flags[3] != 0;
    if (qb) { if (eb) attn_reg_body<true , true >(Qw, Ks, Vs, idxb, emb, out, Klds, Vtlds, Plds, qe, Ilds);
              else    attn_reg_body<true , false>(Qw, Ks, Vs, idxb, emb, out, Klds, Vtlds, Plds, qe, Ilds); }
    else    { if (eb) attn_reg_body<false, true >(Qw, Ks, Vs, idxb, emb, out, Klds, Vtlds, Plds, qe, Ilds);
              else    attn_reg_body<false, false>(Qw, Ks, Vs, idxb, emb, out, Klds, Vtlds, Plds, qe, Ilds); }
}

extern "C" void kernel_launch(void* const* d_in, const int* in_sizes, int n_in,
                              void* d_out, int out_size, void* d_ws, size_t ws_size,
                              hipStream_t stream) {
    const void* query = d_in[0];
    const void* key   = d_in[1];
    const void* value = d_in[2];
    const void* tpos  = d_in[3];
    const void* Wq    = d_in[4];
    const void* bq    = d_in[5];
    const void* Wk    = d_in[6];
    const void* bk    = d_in[7];
    const void* Wv    = d_in[8];
    const void* bv    = d_in[9];
    const void* emb   = d_in[10];

    int*           flags = (int*)d_ws;
    unsigned char* idxb  = (unsigned char*)d_ws + IDX_OFF;
    void*          Kw    = (char*)d_ws + K_OFF;
    void*          Vw    = (char*)d_ws + V_OFF;
    short*         Wbf   = (short*)((char*)d_ws + WBF_OFF);
    short*         Xbf   = (short*)((char*)d_ws + XBF_OFF);
    short*         Vtg   = (short*)((char*)d_ws + VT_OFF);   // overlays Xbf post-proj
    void*          Qw    = d_out;   // Q staged in d_out

    const bool tierA = ws_size >= WS_TIER_A;
    const bool tierB = !tierA && ws_size >= WS_TIER_B;

    detect_kernel<<<4, 64, 0, stream>>>(
        (const unsigned int*)query, (const unsigned int*)tpos,
        (const unsigned int*)Wq, (const unsigned int*)emb, flags);

    if (tierA)
        conv_kernel<<<5472, 256, 0, stream>>>(query, key, value, Wq, Wk, Wv, flags, Xbf, Wbf, 1);
    else if (tierB)
        conv_kernel<<<864, 256, 0, stream>>>(query, key, value, Wq, Wk, Wv, flags, Xbf, Wbf, 0);

    idx_kernel<<<dim3(16, 16, Bsz), 256, 0, stream>>>(tpos, flags, idxb);

    if (tierA)
        proj_kernel<<<dim3(64, 6, 3), 256, 0, stream>>>(
            Xbf, Xbf + NXz, Xbf + 2 * NXz,
            Wbf, bq, Wbf + NWz, bk, Wbf + 2 * NWz, bv,
            Qw, Kw, Vw, flags, 1, 1);
    else if (tierB)
        proj_kernel<<<dim3(64, 6, 3), 256, 0, stream>>>(
            query, key, value,
            Wbf, bq, Wbf + NWz, bk, Wbf + 2 * NWz, bv,
            Qw, Kw, Vw, flags, 0, 1);
    else
        proj_kernel<<<dim3(64, 6, 3), 256, 0, stream>>>(
            query, key, value, Wq, bq, Wk, bk, Wv, bv,
            Qw, Kw, Vw, flags, 0, 0);

    if (tierA) {
        vt_kernel<<<dim3(16, Hn, Bsz), 256, 0, stream>>>((const short*)Vw, Vtg);
        attn_dma_kernel<<<dim3(16, Hn, Bsz), 256, 0, stream>>>(
            Qw, (const short*)Kw, (const short*)Vtg, idxb, emb, d_out, flags);
    } else {
        attn_reg_kernel<<<dim3(16, Hn, Bsz), 256, 0, stream>>>(
            Qw, (const short*)Kw, (const short*)Vw, idxb, emb, d_out, flags);
    }
}